// Round 1
// baseline (640.447 us; speedup 1.0000x reference)
//
#include <hip/hip_runtime.h>
#include <hip/hip_bf16.h>

// Problem constants
#define B_ 4
#define S_ 2048
#define D_ 768
#define H_ 12
#define HD_ 64

typedef __attribute__((ext_vector_type(8))) short bf16x8;   // 8 bf16 in 4 VGPRs
typedef __attribute__((ext_vector_type(4))) float floatx4;  // MFMA C/D frag

__device__ __forceinline__ unsigned short f2bf(float x) {
    union { float f; unsigned int u; } v; v.f = x;
    unsigned int r = v.u + 0x7fffu + ((v.u >> 16) & 1u);  // RNE
    return (unsigned short)(r >> 16);
}

// ---------------- cast kernels ----------------
__global__ void cast_f32_bf16(const float* __restrict__ src,
                              unsigned short* __restrict__ dst, int n4) {
    int i = blockIdx.x * 256 + threadIdx.x;
    if (i >= n4) return;
    float4 f = ((const float4*)src)[i];
    ushort4 o;
    o.x = f2bf(f.x); o.y = f2bf(f.y); o.z = f2bf(f.z); o.w = f2bf(f.w);
    ((ushort4*)dst)[i] = o;
}

__global__ void cast_w4(const float* __restrict__ w0, const float* __restrict__ w1,
                        const float* __restrict__ w2, const float* __restrict__ w3,
                        unsigned short* __restrict__ dst, int n4 /* per weight */) {
    const float* src = (blockIdx.y == 0) ? w0 : (blockIdx.y == 1) ? w1
                     : (blockIdx.y == 2) ? w2 : w3;
    unsigned short* d = dst + (size_t)blockIdx.y * (size_t)n4 * 4;
    int i = blockIdx.x * 256 + threadIdx.x;
    if (i >= n4) return;
    float4 f = ((const float4*)src)[i];
    ushort4 o;
    o.x = f2bf(f.x); o.y = f2bf(f.y); o.z = f2bf(f.z); o.w = f2bf(f.w);
    ((ushort4*)d)[i] = o;
}

// ---------------- QKV projection GEMM ----------------
// C[m][n] = X[m][:]. W[n][:] + bias[n]; M=8192 (b*2048+s), N=768 (h*64+hd), K=768
// 128x128 tile, BK=32, 4 waves each computing 64x64 via 4x4 of 16x16x32 MFMA.
// Output scattered to [B,H,S,HD] bf16.
__global__ __launch_bounds__(256) void qkv_gemm(
    const unsigned short* __restrict__ Xb,
    const unsigned short* __restrict__ Wq, const unsigned short* __restrict__ Wk,
    const unsigned short* __restrict__ Wv,
    const float* __restrict__ bq, const float* __restrict__ bk,
    const float* __restrict__ bv,
    unsigned short* __restrict__ Qo, unsigned short* __restrict__ Ko,
    unsigned short* __restrict__ Vo)
{
    const int z = blockIdx.z;
    const unsigned short* W = (z == 0) ? Wq : (z == 1) ? Wk : Wv;
    const float* bias = (z == 0) ? bq : (z == 1) ? bk : bv;
    unsigned short* Out = (z == 0) ? Qo : (z == 1) ? Ko : Vo;

    const int m0 = blockIdx.x * 128;
    const int n0 = blockIdx.y * 128;

    __shared__ alignas(16) unsigned short As[128 * 32];
    __shared__ alignas(16) unsigned short Bs[128 * 32];

    const int t = threadIdx.x;
    const int lane = t & 63, w = t >> 6;
    const int c = lane & 15, quad = lane >> 4;
    const int wm = (w & 1) * 64, wn = (w >> 1) * 64;

    floatx4 acc[4][4];
#pragma unroll
    for (int i = 0; i < 4; i++)
#pragma unroll
        for (int j = 0; j < 4; j++) acc[i][j] = (floatx4){0.f, 0.f, 0.f, 0.f};

    for (int k0 = 0; k0 < 768; k0 += 32) {
#pragma unroll
        for (int i = 0; i < 2; i++) {
            int idx = i * 256 + t;        // 0..511
            int row = idx >> 2;           // 4 x uint4 per 32-elem row
            int c8 = (idx & 3) * 8;
            *(uint4*)&As[row * 32 + c8] =
                *(const uint4*)&Xb[(size_t)(m0 + row) * 768 + k0 + c8];
            *(uint4*)&Bs[row * 32 + c8] =
                *(const uint4*)&W[(size_t)(n0 + row) * 768 + k0 + c8];
        }
        __syncthreads();
        bf16x8 a[4], b[4];
#pragma unroll
        for (int i = 0; i < 4; i++)
            a[i] = *(const bf16x8*)&As[(wm + i * 16 + c) * 32 + quad * 8];
#pragma unroll
        for (int j = 0; j < 4; j++)
            b[j] = *(const bf16x8*)&Bs[(wn + j * 16 + c) * 32 + quad * 8];
#pragma unroll
        for (int i = 0; i < 4; i++)
#pragma unroll
            for (int j = 0; j < 4; j++)
                acc[i][j] = __builtin_amdgcn_mfma_f32_16x16x32_bf16(
                    a[i], b[j], acc[i][j], 0, 0, 0);
        __syncthreads();
    }

#pragma unroll
    for (int i = 0; i < 4; i++) {
#pragma unroll
        for (int j = 0; j < 4; j++) {
            int nn = n0 + wn + j * 16 + c;
            float bias_n = bias[nn];
            int hh = nn >> 6, dd = nn & 63;
#pragma unroll
            for (int r = 0; r < 4; r++) {
                int mm = m0 + wm + i * 16 + quad * 4 + r;
                int bb = mm >> 11, ss = mm & 2047;
                float v = acc[i][j][r] + bias_n;
                Out[(((size_t)(bb * H_ + hh)) * S_ + ss) * 64 + dd] = f2bf(v);
            }
        }
    }
}

// ---------------- output projection GEMM ----------------
__global__ __launch_bounds__(256) void out_gemm(
    const unsigned short* __restrict__ Cb, const unsigned short* __restrict__ Wo,
    const float* __restrict__ bo, float* __restrict__ out)
{
    const int m0 = blockIdx.x * 128;
    const int n0 = blockIdx.y * 128;

    __shared__ alignas(16) unsigned short As[128 * 32];
    __shared__ alignas(16) unsigned short Bs[128 * 32];

    const int t = threadIdx.x;
    const int lane = t & 63, w = t >> 6;
    const int c = lane & 15, quad = lane >> 4;
    const int wm = (w & 1) * 64, wn = (w >> 1) * 64;

    floatx4 acc[4][4];
#pragma unroll
    for (int i = 0; i < 4; i++)
#pragma unroll
        for (int j = 0; j < 4; j++) acc[i][j] = (floatx4){0.f, 0.f, 0.f, 0.f};

    for (int k0 = 0; k0 < 768; k0 += 32) {
#pragma unroll
        for (int i = 0; i < 2; i++) {
            int idx = i * 256 + t;
            int row = idx >> 2;
            int c8 = (idx & 3) * 8;
            *(uint4*)&As[row * 32 + c8] =
                *(const uint4*)&Cb[(size_t)(m0 + row) * 768 + k0 + c8];
            *(uint4*)&Bs[row * 32 + c8] =
                *(const uint4*)&Wo[(size_t)(n0 + row) * 768 + k0 + c8];
        }
        __syncthreads();
        bf16x8 a[4], b[4];
#pragma unroll
        for (int i = 0; i < 4; i++)
            a[i] = *(const bf16x8*)&As[(wm + i * 16 + c) * 32 + quad * 8];
#pragma unroll
        for (int j = 0; j < 4; j++)
            b[j] = *(const bf16x8*)&Bs[(wn + j * 16 + c) * 32 + quad * 8];
#pragma unroll
        for (int i = 0; i < 4; i++)
#pragma unroll
            for (int j = 0; j < 4; j++)
                acc[i][j] = __builtin_amdgcn_mfma_f32_16x16x32_bf16(
                    a[i], b[j], acc[i][j], 0, 0, 0);
        __syncthreads();
    }

#pragma unroll
    for (int i = 0; i < 4; i++) {
#pragma unroll
        for (int j = 0; j < 4; j++) {
            int nn = n0 + wn + j * 16 + c;
            float bias_n = bo[nn];
#pragma unroll
            for (int r = 0; r < 4; r++) {
                int mm = m0 + wm + i * 16 + quad * 4 + r;
                out[(size_t)mm * 768 + nn] = acc[i][j][r] + bias_n;
            }
        }
    }
}

// ---------------- flash attention ----------------
// grid: (qt=S/64, bh=48). block = 256 (4 waves). Wave w owns q-rows
// [qt*64 + w*16, +16). K-tiles of 64. Online softmax with -1e30 sentinel.
__global__ __launch_bounds__(256) void attn(
    const unsigned short* __restrict__ Q, const unsigned short* __restrict__ K,
    const unsigned short* __restrict__ V, const int* __restrict__ mask,
    unsigned short* __restrict__ ctx)
{
    const int qt = blockIdx.x;
    const int bh = blockIdx.y;
    const int b = bh / H_, h = bh % H_;

    const unsigned short* Qp = Q + (size_t)bh * S_ * 64 + (size_t)qt * 64 * 64;
    const unsigned short* Kp = K + (size_t)bh * S_ * 64;
    const unsigned short* Vp = V + (size_t)bh * S_ * 64;
    const int* maskp = mask + (size_t)h * S_ * S_;

    __shared__ alignas(16) unsigned short Qs[64 * 64];
    __shared__ alignas(16) unsigned short Ks[64 * 64];
    __shared__ alignas(16) unsigned short Vs[64 * 64];   // transposed: Vs[d][k]
    __shared__ alignas(16) unsigned short Ps[4][16 * 64];

    const int t = threadIdx.x;
    const int lane = t & 63, w = t >> 6;
    const int c = lane & 15, quad = lane >> 4;

    // Q tile: 64x64 shorts = 512 uint4
#pragma unroll
    for (int i = 0; i < 2; i++) {
        int idx = i * 256 + t;
        int row = idx >> 3, c8 = (idx & 7) * 8;
        *(uint4*)&Qs[row * 64 + c8] = *(const uint4*)&Qp[(size_t)row * 64 + c8];
    }

    floatx4 acc_o[4];
#pragma unroll
    for (int i = 0; i < 4; i++) acc_o[i] = (floatx4){0.f, 0.f, 0.f, 0.f};
    float m_i[4], l_i[4];
#pragma unroll
    for (int r = 0; r < 4; r++) { m_i[r] = -1e30f; l_i[r] = 0.f; }

    for (int kt = 0; kt < S_ / 64; kt++) {
        // stage K row-major, V transposed
#pragma unroll
        for (int i = 0; i < 2; i++) {
            int idx = i * 256 + t;
            int row = idx >> 3, c8 = (idx & 7) * 8;
            *(uint4*)&Ks[row * 64 + c8] =
                *(const uint4*)&Kp[(size_t)(kt * 64 + row) * 64 + c8];
            uint4 vv = *(const uint4*)&Vp[(size_t)(kt * 64 + row) * 64 + c8];
            const unsigned short* vs = (const unsigned short*)&vv;
#pragma unroll
            for (int j = 0; j < 8; j++) Vs[(c8 + j) * 64 + row] = vs[j];
        }
        __syncthreads();

        // S = Q K^T (16 q-rows x 64 k-cols per wave)
        bf16x8 aq0 = *(const bf16x8*)&Qs[(w * 16 + c) * 64 + quad * 8];
        bf16x8 aq1 = *(const bf16x8*)&Qs[(w * 16 + c) * 64 + 32 + quad * 8];
        floatx4 sacc[4];
#pragma unroll
        for (int nt = 0; nt < 4; nt++) {
            bf16x8 bk0 = *(const bf16x8*)&Ks[(nt * 16 + c) * 64 + quad * 8];
            bf16x8 bk1 = *(const bf16x8*)&Ks[(nt * 16 + c) * 64 + 32 + quad * 8];
            floatx4 zz = (floatx4){0.f, 0.f, 0.f, 0.f};
            zz = __builtin_amdgcn_mfma_f32_16x16x32_bf16(aq0, bk0, zz, 0, 0, 0);
            zz = __builtin_amdgcn_mfma_f32_16x16x32_bf16(aq1, bk1, zz, 0, 0, 0);
            sacc[nt] = zz;
        }

        // online softmax per q-row (row r of this wave's strip lives in the
        // 16 lanes of this quad at reg r)
        float p[4][4];   // [nt][r]
        float alpha[4];
#pragma unroll
        for (int r = 0; r < 4; r++) {
            int qrow = qt * 64 + w * 16 + quad * 4 + r;
            float sv[4];
#pragma unroll
            for (int nt = 0; nt < 4; nt++) {
                float s = sacc[nt][r] * 0.125f;   // 1/sqrt(64)
                int kcol = kt * 64 + nt * 16 + c;
                if (maskp[(size_t)qrow * S_ + kcol] == 0) s = -1e30f;
                sv[nt] = s;
            }
            float tmax = fmaxf(fmaxf(sv[0], sv[1]), fmaxf(sv[2], sv[3]));
#pragma unroll
            for (int o = 1; o < 16; o <<= 1) tmax = fmaxf(tmax, __shfl_xor(tmax, o, 64));
            float mnew = fmaxf(m_i[r], tmax);
            float al = __expf(m_i[r] - mnew);
            float rs = 0.f;
#pragma unroll
            for (int nt = 0; nt < 4; nt++) {
                float pv = __expf(sv[nt] - mnew);
                p[nt][r] = pv;
                rs += pv;
            }
#pragma unroll
            for (int o = 1; o < 16; o <<= 1) rs += __shfl_xor(rs, o, 64);
            l_i[r] = l_i[r] * al + rs;
            m_i[r] = mnew;
            alpha[r] = al;
        }
#pragma unroll
        for (int nt = 0; nt < 4; nt++)
#pragma unroll
            for (int r = 0; r < 4; r++) acc_o[nt][r] *= alpha[r];

        // P: C-layout -> LDS -> A-layout
#pragma unroll
        for (int nt = 0; nt < 4; nt++)
#pragma unroll
            for (int r = 0; r < 4; r++)
                Ps[w][(quad * 4 + r) * 64 + nt * 16 + c] = f2bf(p[nt][r]);
        __syncthreads();

        bf16x8 ap0 = *(const bf16x8*)&Ps[w][c * 64 + quad * 8];
        bf16x8 ap1 = *(const bf16x8*)&Ps[w][c * 64 + 32 + quad * 8];
#pragma unroll
        for (int nt = 0; nt < 4; nt++) {
            bf16x8 bv0 = *(const bf16x8*)&Vs[(nt * 16 + c) * 64 + quad * 8];
            bf16x8 bv1 = *(const bf16x8*)&Vs[(nt * 16 + c) * 64 + 32 + quad * 8];
            acc_o[nt] = __builtin_amdgcn_mfma_f32_16x16x32_bf16(ap0, bv0, acc_o[nt], 0, 0, 0);
            acc_o[nt] = __builtin_amdgcn_mfma_f32_16x16x32_bf16(ap1, bv1, acc_o[nt], 0, 0, 0);
        }
        __syncthreads();   // protect Ks/Vs/Ps before next staging
    }

    // epilogue: ctx[b][s][h*64+d] bf16
#pragma unroll
    for (int nt = 0; nt < 4; nt++) {
#pragma unroll
        for (int r = 0; r < 4; r++) {
            int qrow = qt * 64 + w * 16 + quad * 4 + r;
            int dd = nt * 16 + c;
            float v = acc_o[nt][r] / l_i[r];
            ctx[((size_t)b * S_ + qrow) * 768 + h * 64 + dd] = f2bf(v);
        }
    }
}

extern "C" void kernel_launch(void* const* d_in, const int* in_sizes, int n_in,
                              void* d_out, int out_size, void* d_ws, size_t ws_size,
                              hipStream_t stream) {
    const float* hs    = (const float*)d_in[0];
    const int*   mask  = (const int*)d_in[1];
    const float* q_w   = (const float*)d_in[2];
    const float* q_b   = (const float*)d_in[3];
    const float* k_w   = (const float*)d_in[4];
    const float* k_b   = (const float*)d_in[5];
    const float* v_w   = (const float*)d_in[6];
    const float* v_b   = (const float*)d_in[7];
    const float* out_w = (const float*)d_in[8];
    const float* out_b = (const float*)d_in[9];
    float* out = (float*)d_out;

    // workspace layout (bf16 elements)
    unsigned short* Xb  = (unsigned short*)d_ws;       // 8192*768
    unsigned short* Wqb = Xb + 6291456;                // 768*768 each, x4 contiguous
    unsigned short* Wkb = Wqb + 589824;
    unsigned short* Wvb = Wkb + 589824;
    unsigned short* Wob = Wvb + 589824;
    unsigned short* Qb  = Wob + 589824;                // [B,H,S,HD]
    unsigned short* Kb  = Qb + 6291456;
    unsigned short* Vb  = Kb + 6291456;
    unsigned short* Cb  = Vb + 6291456;                // ctx [B,S,D]

    cast_f32_bf16<<<6144, 256, 0, stream>>>(hs, Xb, 1572864);
    cast_w4<<<dim3(576, 4), 256, 0, stream>>>(q_w, k_w, v_w, out_w, Wqb, 147456);
    qkv_gemm<<<dim3(64, 6, 3), 256, 0, stream>>>(Xb, Wqb, Wkb, Wvb,
                                                 q_b, k_b, v_b, Qb, Kb, Vb);
    attn<<<dim3(32, 48), 256, 0, stream>>>(Qb, Kb, Vb, mask, Cb);
    out_gemm<<<dim3(64, 6), 256, 0, stream>>>(Cb, Wob, out_b, out);
}